// Round 1
// baseline (426.061 us; speedup 1.0000x reference)
//
#include <hip/hip_runtime.h>
#include <hip/hip_bf16.h>
#include <math.h>

#define L 256
#define E 128
#define H 4
#define C 32
#define P (L*L)  // 65536

// ---------------------------------------------------------------------------
// Kernel A: LayerNorm + projections (q,k,v,sigmoid(fu)) + pair_bias
// grid 1024 blocks x 256 threads; each block handles 64 positions.
// ---------------------------------------------------------------------------
__device__ __forceinline__ void do_proj(const float* __restrict__ Wm,
                                        const float* __restrict__ xb,
                                        int cg, float4 acc[8]) {
  for (int e = 0; e < 128; ++e) {
    float4 w = ((const float4*)(Wm + (size_t)e * 128))[cg];
    #pragma unroll
    for (int i = 0; i < 8; ++i) {
      float xv = xb[i * 129 + e];
      acc[i].x = fmaf(xv, w.x, acc[i].x);
      acc[i].y = fmaf(xv, w.y, acc[i].y);
      acc[i].z = fmaf(xv, w.z, acc[i].z);
      acc[i].w = fmaf(xv, w.w, acc[i].w);
    }
  }
}

__global__ __launch_bounds__(256) void k_ln_proj(
    const float* __restrict__ pr, const float* __restrict__ gamma,
    const float* __restrict__ beta, const float* __restrict__ Wq,
    const float* __restrict__ Wk, const float* __restrict__ Wv,
    const float* __restrict__ Wb, const float* __restrict__ Wfu,
    const float* __restrict__ bfu,
    float* __restrict__ qo, float* __restrict__ ko, float* __restrict__ vo,
    float* __restrict__ gfo, float* __restrict__ pbo)
{
  __shared__ float x[64 * 129];
  const int tid = threadIdx.x;
  const int base = blockIdx.x * 64;

  // --- phase 1: LayerNorm, 4 threads per position ---
  {
    const int pl = tid >> 2, sub = tid & 3;
    const float4* src = (const float4*)(pr + (size_t)(base + pl) * 128 + sub * 32);
    float4 r[8];
    float s = 0.f, ss = 0.f;
    #pragma unroll
    for (int j = 0; j < 8; ++j) {
      r[j] = src[j];
      s += r[j].x + r[j].y + r[j].z + r[j].w;
      ss += r[j].x * r[j].x + r[j].y * r[j].y + r[j].z * r[j].z + r[j].w * r[j].w;
    }
    s  += __shfl_xor(s, 1, 4);  s  += __shfl_xor(s, 2, 4);
    ss += __shfl_xor(ss, 1, 4); ss += __shfl_xor(ss, 2, 4);
    const float mu   = s * 0.0078125f;            // /128
    const float var  = ss * 0.0078125f - mu * mu;
    const float rstd = rsqrtf(var + 1e-5f);
    const float4* g4 = (const float4*)(gamma + sub * 32);
    const float4* b4 = (const float4*)(beta + sub * 32);
    float* xr = x + pl * 129 + sub * 32;
    #pragma unroll
    for (int j = 0; j < 8; ++j) {
      float4 gg = g4[j], bb = b4[j];
      xr[4 * j + 0] = (r[j].x - mu) * rstd * gg.x + bb.x;
      xr[4 * j + 1] = (r[j].y - mu) * rstd * gg.y + bb.y;
      xr[4 * j + 2] = (r[j].z - mu) * rstd * gg.z + bb.z;
      xr[4 * j + 3] = (r[j].w - mu) * rstd * gg.w + bb.w;
    }
  }
  __syncthreads();

  // --- phase 3: pair_bias = x @ Wb, one (pos,h) per thread ---
  {
    const int p = tid >> 2, hh = tid & 3;
    const float* xp = x + p * 129;
    float a = 0.f;
    #pragma unroll 4
    for (int e = 0; e < 128; ++e) a = fmaf(xp[e], Wb[e * 4 + hh], a);
    pbo[(size_t)(base + p) * 4 + hh] = a;
  }

  // --- phase 2: projections. thread = (col group cg of 4, pos group pg of 8)
  const int cg = tid & 31, pg = tid >> 5;
  const float* xb = x + (pg * 8) * 129;
  float4 acc[8];

  // Wq (pre-scaled by C^-0.5)
  #pragma unroll
  for (int i = 0; i < 8; ++i) acc[i] = make_float4(0.f, 0.f, 0.f, 0.f);
  do_proj(Wq, xb, cg, acc);
  {
    const float sc = 0.17677669529663689f; // 32^-0.5
    #pragma unroll
    for (int i = 0; i < 8; ++i) {
      float4 o = make_float4(acc[i].x * sc, acc[i].y * sc, acc[i].z * sc, acc[i].w * sc);
      ((float4*)(qo + (size_t)(base + pg * 8 + i) * 128))[cg] = o;
    }
  }

  // Wk
  #pragma unroll
  for (int i = 0; i < 8; ++i) acc[i] = make_float4(0.f, 0.f, 0.f, 0.f);
  do_proj(Wk, xb, cg, acc);
  #pragma unroll
  for (int i = 0; i < 8; ++i)
    ((float4*)(ko + (size_t)(base + pg * 8 + i) * 128))[cg] = acc[i];

  // Wv
  #pragma unroll
  for (int i = 0; i < 8; ++i) acc[i] = make_float4(0.f, 0.f, 0.f, 0.f);
  do_proj(Wv, xb, cg, acc);
  #pragma unroll
  for (int i = 0; i < 8; ++i)
    ((float4*)(vo + (size_t)(base + pg * 8 + i) * 128))[cg] = acc[i];

  // Wfu -> sigmoid(x@Wfu + bfu)
  #pragma unroll
  for (int i = 0; i < 8; ++i) acc[i] = make_float4(0.f, 0.f, 0.f, 0.f);
  do_proj(Wfu, xb, cg, acc);
  {
    float4 bb = ((const float4*)bfu)[cg];
    #pragma unroll
    for (int i = 0; i < 8; ++i) {
      float4 t = make_float4(acc[i].x + bb.x, acc[i].y + bb.y,
                             acc[i].z + bb.z, acc[i].w + bb.w);
      float4 o;
      o.x = 1.f / (1.f + __expf(-t.x));
      o.y = 1.f / (1.f + __expf(-t.y));
      o.z = 1.f / (1.f + __expf(-t.z));
      o.w = 1.f / (1.f + __expf(-t.w));
      ((float4*)(gfo + (size_t)(base + pg * 8 + i) * 128))[cg] = o;
    }
  }
}

// ---------------------------------------------------------------------------
// Kernel A2: T[h][v][q] = mask[q,v] + pair_bias[q,v,h]  (tiled transpose)
// grid (8,8) x 256 threads, 32x32 tiles.
// ---------------------------------------------------------------------------
__global__ __launch_bounds__(256) void k_bias(
    const float* __restrict__ mask, const float* __restrict__ pb,
    float* __restrict__ T)
{
  __shared__ float tm[32 * 33];
  __shared__ float tp[4][32 * 33];
  const int tid = threadIdx.x;
  const int qi0 = blockIdx.x * 32, vi0 = blockIdx.y * 32;
  {
    const int lv = tid & 31, g = tid >> 5;
    #pragma unroll
    for (int r = 0; r < 4; ++r) {
      int lq = g * 4 + r;
      int pos = (qi0 + lq) * 256 + vi0 + lv;
      tm[lq * 33 + lv] = mask[pos];
      float4 b = ((const float4*)pb)[pos];
      tp[0][lq * 33 + lv] = b.x;
      tp[1][lq * 33 + lv] = b.y;
      tp[2][lq * 33 + lv] = b.z;
      tp[3][lq * 33 + lv] = b.w;
    }
  }
  __syncthreads();
  {
    const int lq = tid & 31, g = tid >> 5;
    #pragma unroll
    for (int r = 0; r < 4; ++r) {
      int lv = g * 4 + r;
      float mm = tm[lq * 33 + lv];
      size_t o = (size_t)(vi0 + lv) * 256 + qi0 + lq;
      T[0 * (size_t)P + o] = mm + tp[0][lq * 33 + lv];
      T[1 * (size_t)P + o] = mm + tp[1][lq * 33 + lv];
      T[2 * (size_t)P + o] = mm + tp[2][lq * 33 + lv];
      T[3 * (size_t)P + o] = mm + tp[3][lq * 33 + lv];
    }
  }
}

// ---------------------------------------------------------------------------
// Kernel B: attention. block = (s,h); thread qi owns one score row.
// scores[qi][vi] = k[s,qi,h,:] . qhat[s,vi,h,:] + T[h][vi][qi]
// softmax over vi (no max subtraction -- scores bounded ~|12|), PV accumulate.
// attn_out aliases k buffer (disjoint (pos, h-cols) per block).
// ---------------------------------------------------------------------------
__global__ __launch_bounds__(256) void k_attn(
    const float* __restrict__ q, const float* __restrict__ k,
    const float* __restrict__ v, const float* __restrict__ T,
    float* __restrict__ ao)
{
  __shared__ float qs[256 * 32];
  __shared__ float vs[256 * 32];
  const int tid = threadIdx.x;
  const int s = blockIdx.x >> 2, h = blockIdx.x & 3;
  const int rowbase = s * 256;

  // stage q,v rows (head h columns) into LDS
  #pragma unroll
  for (int k8 = 0; k8 < 8; ++k8) {
    int i4 = tid + 256 * k8;           // 2048 float4s
    int vi = i4 >> 3, c4 = i4 & 7;
    const float* qsrc = q + (size_t)(rowbase + vi) * 128 + h * 32 + c4 * 4;
    const float* vsrc = v + (size_t)(rowbase + vi) * 128 + h * 32 + c4 * 4;
    float4 qq = *((const float4*)qsrc);
    float4 vv = *((const float4*)vsrc);
    *((float4*)(qs + vi * 32 + c4 * 4)) = qq;
    *((float4*)(vs + vi * 32 + c4 * 4)) = vv;
  }
  // k row into registers (read BEFORE any aliased write can happen)
  const int qi = tid;
  float4 kr[8];
  {
    const float4* kp4 = (const float4*)(k + (size_t)(rowbase + qi) * 128 + h * 32);
    #pragma unroll
    for (int j = 0; j < 8; ++j) kr[j] = kp4[j];
  }
  __syncthreads();

  float4 acc[8];
  #pragma unroll
  for (int j = 0; j < 8; ++j) acc[j] = make_float4(0.f, 0.f, 0.f, 0.f);
  float l = 0.f;
  const float* Tp = T + (size_t)h * P + qi;

  for (int vi = 0; vi < 256; ++vi) {
    const float4* qrow = (const float4*)(qs + vi * 32);
    float s0 = 0.f, s1 = 0.f, s2 = 0.f, s3 = 0.f;
    #pragma unroll
    for (int j = 0; j < 8; j += 4) {
      float4 a0 = qrow[j + 0], a1 = qrow[j + 1], a2 = qrow[j + 2], a3 = qrow[j + 3];
      s0 = fmaf(kr[j + 0].x, a0.x, s0); s0 = fmaf(kr[j + 0].y, a0.y, s0);
      s0 = fmaf(kr[j + 0].z, a0.z, s0); s0 = fmaf(kr[j + 0].w, a0.w, s0);
      s1 = fmaf(kr[j + 1].x, a1.x, s1); s1 = fmaf(kr[j + 1].y, a1.y, s1);
      s1 = fmaf(kr[j + 1].z, a1.z, s1); s1 = fmaf(kr[j + 1].w, a1.w, s1);
      s2 = fmaf(kr[j + 2].x, a2.x, s2); s2 = fmaf(kr[j + 2].y, a2.y, s2);
      s2 = fmaf(kr[j + 2].z, a2.z, s2); s2 = fmaf(kr[j + 2].w, a2.w, s2);
      s3 = fmaf(kr[j + 3].x, a3.x, s3); s3 = fmaf(kr[j + 3].y, a3.y, s3);
      s3 = fmaf(kr[j + 3].z, a3.z, s3); s3 = fmaf(kr[j + 3].w, a3.w, s3);
    }
    float sc = (s0 + s1) + (s2 + s3) + Tp[(size_t)vi * 256];
    float e = __expf(sc);
    l += e;
    const float4* vrow = (const float4*)(vs + vi * 32);
    #pragma unroll
    for (int j = 0; j < 8; ++j) {
      float4 vv = vrow[j];
      acc[j].x = fmaf(e, vv.x, acc[j].x);
      acc[j].y = fmaf(e, vv.y, acc[j].y);
      acc[j].z = fmaf(e, vv.z, acc[j].z);
      acc[j].w = fmaf(e, vv.w, acc[j].w);
    }
  }

  const float inv = 1.f / l;
  float4* aop = (float4*)(ao + (size_t)(rowbase + qi) * 128 + h * 32);
  #pragma unroll
  for (int j = 0; j < 8; ++j) {
    float4 o = make_float4(acc[j].x * inv, acc[j].y * inv, acc[j].z * inv, acc[j].w * inv);
    aop[j] = o;
  }
}

// ---------------------------------------------------------------------------
// Kernel C: out = (attn_out * sigmoid_fu) @ Wo + bo
// grid 1024 x 256; block handles 64 positions.
// ---------------------------------------------------------------------------
__global__ __launch_bounds__(256) void k_gate_out(
    const float* __restrict__ ao, const float* __restrict__ gfu,
    const float* __restrict__ Wo, const float* __restrict__ bo,
    float* __restrict__ out)
{
  __shared__ float g[64 * 129];
  const int tid = threadIdx.x;
  const int base = blockIdx.x * 64;

  #pragma unroll
  for (int k8 = 0; k8 < 8; ++k8) {
    int i4 = tid + 256 * k8;          // 2048 float4s = 64x128 floats
    int pl = i4 >> 5, c4 = i4 & 31;
    float4 a = ((const float4*)(ao + (size_t)base * 128))[i4];
    float4 f = ((const float4*)(gfu + (size_t)base * 128))[i4];
    g[pl * 129 + c4 * 4 + 0] = a.x * f.x;
    g[pl * 129 + c4 * 4 + 1] = a.y * f.y;
    g[pl * 129 + c4 * 4 + 2] = a.z * f.z;
    g[pl * 129 + c4 * 4 + 3] = a.w * f.w;
  }
  __syncthreads();

  const int cg = tid & 31, pg = tid >> 5;
  const float* gb = g + (pg * 8) * 129;
  float4 acc[8];
  #pragma unroll
  for (int i = 0; i < 8; ++i) acc[i] = make_float4(0.f, 0.f, 0.f, 0.f);
  for (int e = 0; e < 128; ++e) {
    float4 w = ((const float4*)(Wo + (size_t)e * 128))[cg];
    #pragma unroll
    for (int i = 0; i < 8; ++i) {
      float gv = gb[i * 129 + e];
      acc[i].x = fmaf(gv, w.x, acc[i].x);
      acc[i].y = fmaf(gv, w.y, acc[i].y);
      acc[i].z = fmaf(gv, w.z, acc[i].z);
      acc[i].w = fmaf(gv, w.w, acc[i].w);
    }
  }
  float4 bb = ((const float4*)bo)[cg];
  #pragma unroll
  for (int i = 0; i < 8; ++i) {
    float4 o = make_float4(acc[i].x + bb.x, acc[i].y + bb.y,
                           acc[i].z + bb.z, acc[i].w + bb.w);
    ((float4*)(out + (size_t)(base + pg * 8 + i) * 128))[cg] = o;
  }
}

// ---------------------------------------------------------------------------
extern "C" void kernel_launch(void* const* d_in, const int* in_sizes, int n_in,
                              void* d_out, int out_size, void* d_ws, size_t ws_size,
                              hipStream_t stream) {
  const float* pr    = (const float*)d_in[0];
  const float* mask  = (const float*)d_in[1];
  const float* gamma = (const float*)d_in[2];
  const float* beta  = (const float*)d_in[3];
  const float* Wq    = (const float*)d_in[4];
  const float* Wk    = (const float*)d_in[5];
  const float* Wv    = (const float*)d_in[6];
  const float* Wb    = (const float*)d_in[7];
  const float* Wfu   = (const float*)d_in[8];
  const float* bfu   = (const float*)d_in[9];
  const float* Wo    = (const float*)d_in[10];
  const float* bo    = (const float*)d_in[11];
  float* out = (float*)d_out;
  float* ws  = (float*)d_ws;

  float* q  = ws;                          // P*E
  float* k  = q  + (size_t)P * E;          // P*E  (aliased as attn_out)
  float* v  = k  + (size_t)P * E;          // P*E
  float* gf = v  + (size_t)P * E;          // P*E
  float* pb = gf + (size_t)P * E;          // P*H
  float* T  = pb + (size_t)P * H;          // H*P

  k_ln_proj<<<1024, 256, 0, stream>>>(pr, gamma, beta, Wq, Wk, Wv, Wb, Wfu, bfu,
                                      q, k, v, gf, pb);
  k_bias<<<dim3(8, 8), 256, 0, stream>>>(mask, pb, T);
  k_attn<<<1024, 256, 0, stream>>>(q, k, v, T, k /* attn_out aliases k */);
  k_gate_out<<<1024, 256, 0, stream>>>(k, gf, Wo, bo, out);
}

// Round 2
// 258.995 us; speedup vs baseline: 1.6451x; 1.6451x over previous
//
#include <hip/hip_runtime.h>
#include <math.h>

#define L 256
#define E 128
#define H 4
#define C 32
#define P (L*L)  // 65536

typedef __bf16 bf16;
typedef __bf16 bf16x8 __attribute__((ext_vector_type(8)));
typedef __bf16 bf16x4 __attribute__((ext_vector_type(4)));
typedef float  f32x4  __attribute__((ext_vector_type(4)));

#define MFMA(a,b,c) __builtin_amdgcn_mfma_f32_16x16x32_bf16((a),(b),(c),0,0,0)

// ---------------------------------------------------------------------------
// k_prep: WT[m][col][e] = W_m[e][col] (bf16, Wq pre-scaled by C^-0.5), WoT too.
// 80 blocks x 256 threads; block = (matrix m, 32x32 tile t).
// ---------------------------------------------------------------------------
__global__ __launch_bounds__(256) void k_prep(
    const float* __restrict__ Wq, const float* __restrict__ Wk,
    const float* __restrict__ Wv, const float* __restrict__ Wfu,
    const float* __restrict__ Wo, bf16* __restrict__ WTcat,
    bf16* __restrict__ WoT)
{
  __shared__ float tile[32][33];
  const int b = blockIdx.x;
  const int m = b >> 4, t = b & 15;
  const float* W = (m==0)?Wq:(m==1)?Wk:(m==2)?Wv:(m==3)?Wfu:Wo;
  bf16* dst = (m < 4) ? (WTcat + (size_t)m * 16384) : WoT;
  const float sc = (m == 0) ? 0.17677669529663689f : 1.0f;
  const int r0 = (t >> 2) * 32, c0 = (t & 3) * 32;
  {
    const int r = threadIdx.x >> 3, c4 = threadIdx.x & 7;
    float4 v = *(const float4*)(W + (size_t)(r0 + r) * 128 + c0 + c4 * 4);
    tile[r][c4*4+0] = v.x; tile[r][c4*4+1] = v.y;
    tile[r][c4*4+2] = v.z; tile[r][c4*4+3] = v.w;
  }
  __syncthreads();
  {
    const int c = threadIdx.x >> 3, e4 = threadIdx.x & 7;
    bf16x4 o;
    o[0] = (bf16)(tile[e4*4+0][c] * sc);
    o[1] = (bf16)(tile[e4*4+1][c] * sc);
    o[2] = (bf16)(tile[e4*4+2][c] * sc);
    o[3] = (bf16)(tile[e4*4+3][c] * sc);
    *(bf16x4*)(dst + (size_t)(c0 + c) * 128 + r0 + e4 * 4) = o;
  }
}

// ---------------------------------------------------------------------------
// k_ln_proj: LN -> bf16 x in LDS; MFMA out^T = WT . x^T per wave.
// wave 0->qb, 1->kb, 2->vbT (transposed global), 3->sigmoid gate gfb.
// Also pair_bias = x @ Wb (fp32).
// ---------------------------------------------------------------------------
__global__ __launch_bounds__(256) void k_ln_proj(
    const float* __restrict__ pr, const float* __restrict__ gamma,
    const float* __restrict__ beta, const float* __restrict__ Wb,
    const float* __restrict__ bfu, const bf16* __restrict__ WTcat,
    bf16* __restrict__ qb, bf16* __restrict__ kb, bf16* __restrict__ vbT,
    bf16* __restrict__ gfb, float* __restrict__ pbo)
{
  __shared__ bf16 xs[64 * 136];
  __shared__ float wbs[512];
  const int tid = threadIdx.x;
  const int base = blockIdx.x * 64;

  wbs[tid] = Wb[tid];
  wbs[tid + 256] = Wb[tid + 256];

  // --- LayerNorm (4 threads per position) ---
  {
    const int pl = tid >> 2, sub = tid & 3;
    const float4* src = (const float4*)(pr + (size_t)(base + pl) * 128 + sub * 32);
    float4 r[8];
    float s = 0.f, ss = 0.f;
    #pragma unroll
    for (int j = 0; j < 8; ++j) {
      r[j] = src[j];
      s  += r[j].x + r[j].y + r[j].z + r[j].w;
      ss += r[j].x*r[j].x + r[j].y*r[j].y + r[j].z*r[j].z + r[j].w*r[j].w;
    }
    s  += __shfl_xor(s, 1, 4);  s  += __shfl_xor(s, 2, 4);
    ss += __shfl_xor(ss, 1, 4); ss += __shfl_xor(ss, 2, 4);
    const float mu   = s * 0.0078125f;
    const float var  = ss * 0.0078125f - mu * mu;
    const float rstd = rsqrtf(var + 1e-5f);
    const float4* g4 = (const float4*)(gamma + sub * 32);
    const float4* b4 = (const float4*)(beta + sub * 32);
    float vals[32];
    #pragma unroll
    for (int j = 0; j < 8; ++j) {
      float4 gg = g4[j], bb = b4[j];
      vals[4*j+0] = (r[j].x - mu) * rstd * gg.x + bb.x;
      vals[4*j+1] = (r[j].y - mu) * rstd * gg.y + bb.y;
      vals[4*j+2] = (r[j].z - mu) * rstd * gg.z + bb.z;
      vals[4*j+3] = (r[j].w - mu) * rstd * gg.w + bb.w;
    }
    bf16* xr = xs + pl * 136 + sub * 32;
    #pragma unroll
    for (int i = 0; i < 4; ++i) {
      bf16x8 o;
      #pragma unroll
      for (int e = 0; e < 8; ++e) o[e] = (bf16)vals[8*i + e];
      *(bf16x8*)(xr + 8 * i) = o;
    }
  }
  __syncthreads();

  // --- pair_bias ---
  {
    const int p = tid >> 2, hh = tid & 3;
    const bf16* xp = xs + p * 136;
    float a = 0.f;
    #pragma unroll 8
    for (int e = 0; e < 128; ++e) a = fmaf((float)xp[e], wbs[e * 4 + hh], a);
    pbo[(size_t)(base + p) * 4 + hh] = a;
  }

  // --- projections via MFMA: out^T = WT . x^T ---
  const int w = tid >> 6, lane = tid & 63, g = lane >> 4, l15 = lane & 15;
  const bf16* wt = WTcat + (size_t)w * 16384;
  bf16x8 af[8][4];
  #pragma unroll
  for (int mt = 0; mt < 8; ++mt)
    #pragma unroll
    for (int kt = 0; kt < 4; ++kt)
      af[mt][kt] = *(const bf16x8*)(wt + (size_t)(16*mt + l15) * 128 + 32*kt + 8*g);

  bf16* outp = (w == 0) ? qb : (w == 1) ? kb : gfb;

  for (int nt = 0; nt < 4; ++nt) {
    bf16x8 bfr[4];
    #pragma unroll
    for (int kt = 0; kt < 4; ++kt)
      bfr[kt] = *(const bf16x8*)(xs + (16*nt + l15) * 136 + 32*kt + 8*g);
    f32x4 acc[8];
    #pragma unroll
    for (int mt = 0; mt < 8; ++mt) acc[mt] = (f32x4){0.f, 0.f, 0.f, 0.f};
    #pragma unroll
    for (int kt = 0; kt < 4; ++kt)
      #pragma unroll
      for (int mt = 0; mt < 8; ++mt)
        acc[mt] = MFMA(af[mt][kt], bfr[kt], acc[mt]);

    const int pos = base + 16 * nt + l15;
    if (w == 2) {
      // v transposed: vbT[col][pos]
      #pragma unroll
      for (int mt = 0; mt < 8; ++mt) {
        #pragma unroll
        for (int r = 0; r < 4; ++r)
          vbT[(size_t)(16*mt + 4*g + r) * P + pos] = (bf16)acc[mt][r];
      }
    } else {
      #pragma unroll
      for (int mt = 0; mt < 8; ++mt) {
        const int col = 16 * mt + 4 * g;
        f32x4 vv = acc[mt];
        if (w == 3) {
          float4 bb = *(const float4*)(bfu + col);
          vv[0] = 1.f / (1.f + __expf(-(vv[0] + bb.x)));
          vv[1] = 1.f / (1.f + __expf(-(vv[1] + bb.y)));
          vv[2] = 1.f / (1.f + __expf(-(vv[2] + bb.z)));
          vv[3] = 1.f / (1.f + __expf(-(vv[3] + bb.w)));
        }
        bf16x4 o;
        o[0] = (bf16)vv[0]; o[1] = (bf16)vv[1];
        o[2] = (bf16)vv[2]; o[3] = (bf16)vv[3];
        *(bf16x4*)(outp + (size_t)pos * 128 + col) = o;
      }
    }
  }
}

// ---------------------------------------------------------------------------
// k_bias: T[h][v][q] = mask[q,v] + pb[q,v,h]  (bf16 output)
// ---------------------------------------------------------------------------
__global__ __launch_bounds__(256) void k_bias(
    const float* __restrict__ mask, const float* __restrict__ pb,
    bf16* __restrict__ T)
{
  __shared__ float tm[32 * 33];
  __shared__ float tp[4][32 * 33];
  const int tid = threadIdx.x;
  const int qi0 = blockIdx.x * 32, vi0 = blockIdx.y * 32;
  {
    const int lv = tid & 31, g = tid >> 5;
    #pragma unroll
    for (int r = 0; r < 4; ++r) {
      int lq = g * 4 + r;
      int pos = (qi0 + lq) * 256 + vi0 + lv;
      tm[lq * 33 + lv] = mask[pos];
      float4 b = ((const float4*)pb)[pos];
      tp[0][lq * 33 + lv] = b.x;
      tp[1][lq * 33 + lv] = b.y;
      tp[2][lq * 33 + lv] = b.z;
      tp[3][lq * 33 + lv] = b.w;
    }
  }
  __syncthreads();
  {
    const int lq = tid & 31, g = tid >> 5;
    #pragma unroll
    for (int r = 0; r < 4; ++r) {
      int lv = g * 4 + r;
      float mm = tm[lq * 33 + lv];
      size_t o = (size_t)(vi0 + lv) * 256 + qi0 + lq;
      T[0 * (size_t)P + o] = (bf16)(mm + tp[0][lq * 33 + lv]);
      T[1 * (size_t)P + o] = (bf16)(mm + tp[1][lq * 33 + lv]);
      T[2 * (size_t)P + o] = (bf16)(mm + tp[2][lq * 33 + lv]);
      T[3 * (size_t)P + o] = (bf16)(mm + tp[3][lq * 33 + lv]);
    }
  }
}

// ---------------------------------------------------------------------------
// k_attn: block=(s,h), 4 waves x 64 q-rows. MFMA QK^T -> softmax -> MFMA PV.
// q staged in LDS (stride 40), P in LDS (stride 264), k/vbT/T from global.
// ---------------------------------------------------------------------------
__global__ __launch_bounds__(256) void k_attn(
    const bf16* __restrict__ qb, const bf16* __restrict__ kb,
    const bf16* __restrict__ vbT, const bf16* __restrict__ T,
    bf16* __restrict__ ao)
{
  __shared__ bf16 qs[256 * 40];       // 20.0 KB
  __shared__ bf16 ps[4][16 * 264];    // 33.0 KB
  const int tid = threadIdx.x;
  const int s = blockIdx.x >> 2, h = blockIdx.x & 3;
  const int rb = s * 256;

  // stage qhat rows (head h) into LDS
  {
    const bf16* src = qb + (size_t)(rb + tid) * 128 + h * 32;
    #pragma unroll
    for (int i = 0; i < 4; ++i)
      *(bf16x8*)(qs + tid * 40 + 8 * i) = *(const bf16x8*)(src + 8 * i);
  }
  __syncthreads();

  const int w = tid >> 6, lane = tid & 63, g = lane >> 4, l15 = lane & 15;
  bf16* psw = ps[w];
  const bf16* Th = T + (size_t)h * P;

  // hoisted PV A-fragments (vbT rows are contiguous in pos)
  bf16x8 av[2][8];
  #pragma unroll
  for (int mt = 0; mt < 2; ++mt)
    #pragma unroll
    for (int kt = 0; kt < 8; ++kt)
      av[mt][kt] = *(const bf16x8*)(vbT + (size_t)(h*32 + 16*mt + l15) * P
                                    + rb + 32*kt + 8*g);

  const f32x4 z = {0.f, 0.f, 0.f, 0.f};

  for (int qt = 0; qt < 4; ++qt) {
    const int q0 = w * 64 + qt * 16;

    // QK^T: scores for 16 q rows x all 256 v
    bf16x8 ak = *(const bf16x8*)(kb + (size_t)(rb + q0 + l15) * 128 + h*32 + 8*g);
    f32x4 sc[16];
    #pragma unroll
    for (int t = 0; t < 16; ++t) {
      bf16x8 bq = *(const bf16x8*)(qs + (16*t + l15) * 40 + 8*g);
      sc[t] = MFMA(ak, bq, z);
    }

    // bias + exp + row sums
    float rs0 = 0.f, rs1 = 0.f, rs2 = 0.f, rs3 = 0.f;
    #pragma unroll
    for (int t = 0; t < 16; ++t) {
      bf16x4 bb = *(const bf16x4*)(Th + (size_t)(16*t + l15) * 256 + q0 + 4*g);
      float e0 = __expf(sc[t][0] + (float)bb[0]); sc[t][0] = e0; rs0 += e0;
      float e1 = __expf(sc[t][1] + (float)bb[1]); sc[t][1] = e1; rs1 += e1;
      float e2 = __expf(sc[t][2] + (float)bb[2]); sc[t][2] = e2; rs2 += e2;
      float e3 = __expf(sc[t][3] + (float)bb[3]); sc[t][3] = e3; rs3 += e3;
    }
    #pragma unroll
    for (int m = 1; m < 16; m <<= 1) {
      rs0 += __shfl_xor(rs0, m, 16);
      rs1 += __shfl_xor(rs1, m, 16);
      rs2 += __shfl_xor(rs2, m, 16);
      rs3 += __shfl_xor(rs3, m, 16);
    }
    const float i0 = 1.f / rs0, i1 = 1.f / rs1, i2 = 1.f / rs2, i3 = 1.f / rs3;

    // normalized P (bf16) to LDS: P[q_local][v], stride 264
    #pragma unroll
    for (int t = 0; t < 16; ++t) {
      const int vcol = 16 * t + l15;
      psw[(4*g + 0) * 264 + vcol] = (bf16)(sc[t][0] * i0);
      psw[(4*g + 1) * 264 + vcol] = (bf16)(sc[t][1] * i1);
      psw[(4*g + 2) * 264 + vcol] = (bf16)(sc[t][2] * i2);
      psw[(4*g + 3) * 264 + vcol] = (bf16)(sc[t][3] * i3);
    }

    // PV: out^T[c][q_local]
    f32x4 o0 = z, o1 = z;
    #pragma unroll
    for (int kt = 0; kt < 8; ++kt) {
      bf16x8 bp = *(const bf16x8*)(psw + l15 * 264 + 32*kt + 8*g);
      o0 = MFMA(av[0][kt], bp, o0);
      o1 = MFMA(av[1][kt], bp, o1);
    }
    const size_t qrow = (size_t)(rb + q0 + l15) * 128 + h * 32;
    bf16x4 p0, p1;
    p0[0] = (bf16)o0[0]; p0[1] = (bf16)o0[1]; p0[2] = (bf16)o0[2]; p0[3] = (bf16)o0[3];
    p1[0] = (bf16)o1[0]; p1[1] = (bf16)o1[1]; p1[2] = (bf16)o1[2]; p1[3] = (bf16)o1[3];
    *(bf16x4*)(ao + qrow + 4*g)      = p0;
    *(bf16x4*)(ao + qrow + 16 + 4*g) = p1;
  }
}

// ---------------------------------------------------------------------------
// k_gate_out: out = (ao * gf) @ Wo + bo via MFMA (out^T = WoT . g^T)
// ---------------------------------------------------------------------------
__global__ __launch_bounds__(256) void k_gate_out(
    const bf16* __restrict__ aob, const bf16* __restrict__ gfb,
    const bf16* __restrict__ WoT, const float* __restrict__ bo,
    float* __restrict__ out)
{
  __shared__ bf16 gs[64 * 136];
  const int tid = threadIdx.x;
  const int base = blockIdx.x * 64;

  #pragma unroll
  for (int it = 0; it < 4; ++it) {
    const int idx = tid + 256 * it;
    bf16x8 a = *(const bf16x8*)(aob + (size_t)base * 128 + idx * 8);
    bf16x8 f = *(const bf16x8*)(gfb + (size_t)base * 128 + idx * 8);
    bf16x8 o;
    #pragma unroll
    for (int j = 0; j < 8; ++j) o[j] = (bf16)((float)a[j] * (float)f[j]);
    *(bf16x8*)(gs + (idx >> 4) * 136 + (idx & 15) * 8) = o;
  }
  __syncthreads();

  const int w = tid >> 6, lane = tid & 63, g = lane >> 4, l15 = lane & 15;
  bf16x8 af[2][4];
  #pragma unroll
  for (int mi = 0; mi < 2; ++mi)
    #pragma unroll
    for (int kt = 0; kt < 4; ++kt)
      af[mi][kt] = *(const bf16x8*)(WoT + (size_t)(16*(2*w + mi) + l15) * 128
                                    + 32*kt + 8*g);

  for (int nt = 0; nt < 4; ++nt) {
    bf16x8 bfr[4];
    #pragma unroll
    for (int kt = 0; kt < 4; ++kt)
      bfr[kt] = *(const bf16x8*)(gs + (16*nt + l15) * 136 + 32*kt + 8*g);
    f32x4 a0 = {0.f,0.f,0.f,0.f}, a1 = {0.f,0.f,0.f,0.f};
    #pragma unroll
    for (int kt = 0; kt < 4; ++kt) {
      a0 = MFMA(af[0][kt], bfr[kt], a0);
      a1 = MFMA(af[1][kt], bfr[kt], a1);
    }
    const int pos = base + 16 * nt + l15;
    {
      const int col = 16 * (2*w + 0) + 4 * g;
      float4 bb = *(const float4*)(bo + col);
      *(float4*)(out + (size_t)pos * 128 + col) =
          make_float4(a0[0] + bb.x, a0[1] + bb.y, a0[2] + bb.z, a0[3] + bb.w);
    }
    {
      const int col = 16 * (2*w + 1) + 4 * g;
      float4 bb = *(const float4*)(bo + col);
      *(float4*)(out + (size_t)pos * 128 + col) =
          make_float4(a1[0] + bb.x, a1[1] + bb.y, a1[2] + bb.z, a1[3] + bb.w);
    }
  }
}

// ---------------------------------------------------------------------------
extern "C" void kernel_launch(void* const* d_in, const int* in_sizes, int n_in,
                              void* d_out, int out_size, void* d_ws, size_t ws_size,
                              hipStream_t stream) {
  const float* pr    = (const float*)d_in[0];
  const float* mask  = (const float*)d_in[1];
  const float* gamma = (const float*)d_in[2];
  const float* beta  = (const float*)d_in[3];
  const float* Wq    = (const float*)d_in[4];
  const float* Wk    = (const float*)d_in[5];
  const float* Wv    = (const float*)d_in[6];
  const float* Wb    = (const float*)d_in[7];
  const float* Wfu   = (const float*)d_in[8];
  const float* bfu   = (const float*)d_in[9];
  const float* Wo    = (const float*)d_in[10];
  const float* bo    = (const float*)d_in[11];
  float* out = (float*)d_out;

  bf16* qb   = (bf16*)d_ws;                       // P*128 bf16
  bf16* kb   = qb  + (size_t)P * 128;
  bf16* vbT  = kb  + (size_t)P * 128;             // [128 cols][P]
  bf16* gfb  = vbT + (size_t)P * 128;
  bf16* aob  = gfb + (size_t)P * 128;
  bf16* T    = aob + (size_t)P * 128;             // H*P bf16
  bf16* WTcat= T   + (size_t)H * P;               // 4*128*128
  bf16* WoT  = WTcat + 4 * 128 * 128;             // 128*128
  float* pb  = (float*)(WoT + 128 * 128 + 128);   // P*4 fp32 (aligned)

  k_prep<<<80, 256, 0, stream>>>(Wq, Wk, Wv, Wfu, Wo, WTcat, WoT);
  k_ln_proj<<<1024, 256, 0, stream>>>(pr, gamma, beta, Wb, bfu, WTcat,
                                      qb, kb, vbT, gfb, pb);
  k_bias<<<dim3(8, 8), 256, 0, stream>>>(mask, pb, T);
  k_attn<<<1024, 256, 0, stream>>>(qb, kb, vbT, T, aob);
  k_gate_out<<<1024, 256, 0, stream>>>(aob, gfb, WoT, bo, out);
}

// Round 3
// 200.122 us; speedup vs baseline: 2.1290x; 1.2942x over previous
//
#include <hip/hip_runtime.h>
#include <math.h>

#define L 256
#define E 128
#define H 4
#define C 32
#define P (L*L)  // 65536

typedef __bf16 bf16;
typedef __bf16 bf16x8 __attribute__((ext_vector_type(8)));
typedef __bf16 bf16x4 __attribute__((ext_vector_type(4)));
typedef float  f32x4  __attribute__((ext_vector_type(4)));

#define MFMA(a,b,c) __builtin_amdgcn_mfma_f32_16x16x32_bf16((a),(b),(c),0,0,0)

// ---------------------------------------------------------------------------
// k_prep: emit weights in MFMA A-fragment order so every A-frag load is one
// coalesced 16B/lane transaction. frag f=mt*4+kt; elem j at lane (g,l15) is
// A[row=16mt+l15][k=32kt+8g+j] = W[k][row] (*C^-0.5 for Wq).
// WbF: rows 0..3 = Wb columns, rows 4..15 zero.
// ---------------------------------------------------------------------------
__global__ __launch_bounds__(256) void k_prep(
    const float* __restrict__ Wq, const float* __restrict__ Wk,
    const float* __restrict__ Wv, const float* __restrict__ Wfu,
    const float* __restrict__ Wo, const float* __restrict__ Wb,
    bf16* __restrict__ WF, bf16* __restrict__ WoF, bf16* __restrict__ WbF)
{
  const int m = blockIdx.x;  // 0..5
  const int lane = threadIdx.x & 63, wv = threadIdx.x >> 6;
  const int g = lane >> 4, l15 = lane & 15;
  if (m < 5) {
    const float* W = (m==0)?Wq:(m==1)?Wk:(m==2)?Wv:(m==3)?Wfu:Wo;
    bf16* dst = (m < 4) ? (WF + (size_t)m * 16384) : WoF;
    const float sc = (m == 0) ? 0.17677669529663689f : 1.0f;
    for (int f = wv; f < 32; f += 4) {
      const int mt = f >> 2, kt = f & 3;
      const int row = 16*mt + l15, k0 = 32*kt + 8*g;
      bf16x8 o;
      #pragma unroll
      for (int j = 0; j < 8; ++j) o[j] = (bf16)(W[(size_t)(k0+j)*128 + row] * sc);
      *(bf16x8*)(dst + ((size_t)f*64 + lane)*8) = o;
    }
  } else {
    const int kt = wv, k0 = 32*kt + 8*g;
    bf16x8 o;
    #pragma unroll
    for (int j = 0; j < 8; ++j)
      o[j] = (l15 < 4) ? (bf16)Wb[(size_t)(k0+j)*4 + l15] : (bf16)0.0f;
    *(bf16x8*)(WbF + ((size_t)kt*64 + lane)*8) = o;
  }
}

// ---------------------------------------------------------------------------
// k_ln_proj: LN -> bf16 x in LDS; per-wave matrix (q,k,v,gate) via MFMA with
// fragment-ordered A loads; pair_bias via MFMA (wave w does positions 16w..).
// Epilogue staged through LDS -> fully coalesced global stores.
// q,k,v head-major [h][P][32]; gate [P][128]; pb [P][4] fp32.
// ---------------------------------------------------------------------------
__global__ __launch_bounds__(256) void k_ln_proj(
    const float* __restrict__ pr, const float* __restrict__ gamma,
    const float* __restrict__ beta, const float* __restrict__ bfu,
    const bf16* __restrict__ WF, const bf16* __restrict__ WbF,
    bf16* __restrict__ qbh, bf16* __restrict__ kbh, bf16* __restrict__ vbh,
    bf16* __restrict__ gfb, float* __restrict__ pbo)
{
  __shared__ bf16 xs[64 * 136];        // 17.0 KB
  __shared__ bf16 stag[4][16 * 136];   // 17.0 KB
  const int tid = threadIdx.x;
  const int base = blockIdx.x * 64;

  // --- LayerNorm (4 threads per position) ---
  {
    const int pl = tid >> 2, sub = tid & 3;
    const float4* src = (const float4*)(pr + (size_t)(base + pl) * 128 + sub * 32);
    float4 r[8];
    float s = 0.f, ss = 0.f;
    #pragma unroll
    for (int j = 0; j < 8; ++j) {
      r[j] = src[j];
      s  += r[j].x + r[j].y + r[j].z + r[j].w;
      ss += r[j].x*r[j].x + r[j].y*r[j].y + r[j].z*r[j].z + r[j].w*r[j].w;
    }
    s  += __shfl_xor(s, 1, 4);  s  += __shfl_xor(s, 2, 4);
    ss += __shfl_xor(ss, 1, 4); ss += __shfl_xor(ss, 2, 4);
    const float mu   = s * 0.0078125f;
    const float var  = ss * 0.0078125f - mu * mu;
    const float rstd = rsqrtf(var + 1e-5f);
    const float4* g4 = (const float4*)(gamma + sub * 32);
    const float4* b4 = (const float4*)(beta + sub * 32);
    bf16* xr = xs + pl * 136 + sub * 32;
    #pragma unroll
    for (int i = 0; i < 4; ++i) {
      float4 r0 = r[2*i], r1 = r[2*i+1];
      float4 gg0 = g4[2*i], gg1 = g4[2*i+1], bb0 = b4[2*i], bb1 = b4[2*i+1];
      bf16x8 o;
      o[0] = (bf16)((r0.x - mu) * rstd * gg0.x + bb0.x);
      o[1] = (bf16)((r0.y - mu) * rstd * gg0.y + bb0.y);
      o[2] = (bf16)((r0.z - mu) * rstd * gg0.z + bb0.z);
      o[3] = (bf16)((r0.w - mu) * rstd * gg0.w + bb0.w);
      o[4] = (bf16)((r1.x - mu) * rstd * gg1.x + bb1.x);
      o[5] = (bf16)((r1.y - mu) * rstd * gg1.y + bb1.y);
      o[6] = (bf16)((r1.z - mu) * rstd * gg1.z + bb1.z);
      o[7] = (bf16)((r1.w - mu) * rstd * gg1.w + bb1.w);
      *(bf16x8*)(xr + 8 * i) = o;
    }
  }
  __syncthreads();

  const int w = tid >> 6, lane = tid & 63, g = lane >> 4, l15 = lane & 15;
  const f32x4 z = {0.f, 0.f, 0.f, 0.f};

  // --- pair_bias via MFMA: wave w covers positions base+16w..base+16w+15 ---
  {
    f32x4 acc = z;
    #pragma unroll
    for (int kt = 0; kt < 4; ++kt) {
      bf16x8 a = *(const bf16x8*)(WbF + ((size_t)kt*64 + lane)*8);
      bf16x8 b = *(const bf16x8*)(xs + (16*w + l15)*136 + 32*kt + 8*g);
      acc = MFMA(a, b, acc);
    }
    if (g == 0)
      *(float4*)(pbo + (size_t)(base + 16*w + l15)*4) =
          make_float4(acc[0], acc[1], acc[2], acc[3]);
  }

  // --- projection: wave w -> matrix w ---
  const bf16* WFw = WF + (size_t)w * 16384;
  bf16* stw = stag[w];

  for (int nt = 0; nt < 4; ++nt) {
    bf16x8 bfr[4];
    #pragma unroll
    for (int kt = 0; kt < 4; ++kt)
      bfr[kt] = *(const bf16x8*)(xs + (16*nt + l15)*136 + 32*kt + 8*g);
    f32x4 acc[8];
    #pragma unroll
    for (int mt = 0; mt < 8; ++mt) acc[mt] = z;
    #pragma unroll
    for (int kt = 0; kt < 4; ++kt)
      #pragma unroll
      for (int mt = 0; mt < 8; ++mt) {
        bf16x8 a = *(const bf16x8*)(WFw + ((size_t)(mt*4 + kt)*64 + lane)*8);
        acc[mt] = MFMA(a, bfr[kt], acc[mt]);
      }

    // epilogue -> LDS staging (D: col=16mt+4g+r, pos=l15)
    #pragma unroll
    for (int mt = 0; mt < 8; ++mt) {
      const int col = 16*mt + 4*g;
      f32x4 vv = acc[mt];
      if (w == 3) {
        float4 bb = *(const float4*)(bfu + col);
        vv[0] = 1.f / (1.f + __expf(-(vv[0] + bb.x)));
        vv[1] = 1.f / (1.f + __expf(-(vv[1] + bb.y)));
        vv[2] = 1.f / (1.f + __expf(-(vv[2] + bb.z)));
        vv[3] = 1.f / (1.f + __expf(-(vv[3] + bb.w)));
      }
      bf16x4 o;
      o[0] = (bf16)vv[0]; o[1] = (bf16)vv[1]; o[2] = (bf16)vv[2]; o[3] = (bf16)vv[3];
      *(bf16x4*)(stw + l15*136 + col) = o;
    }

    // coalesced global store (same-wave LDS ordering guarantees visibility)
    #pragma unroll
    for (int i = 0; i < 4; ++i) {
      const int flat = i*512 + lane*8;
      const int p = flat >> 7, c = flat & 127;
      bf16x8 val = *(const bf16x8*)(stw + p*136 + c);
      if (w == 3) {
        *(bf16x8*)(gfb + ((size_t)(base + 16*nt + p))*128 + c) = val;
      } else {
        bf16* dst = (w == 0) ? qbh : (w == 1) ? kbh : vbh;
        const int h = c >> 5;
        *(bf16x8*)(dst + ((size_t)h*P + base + 16*nt + p)*32 + (c & 31)) = val;
      }
    }
  }
}

// ---------------------------------------------------------------------------
// k_bias: T4[h][qt][v][q16] = mask[q,v] + pb[q,v,h]  (bf16, coalesced writes)
// grid 64 = (h*16 + qt), 256 threads (v = tid).
// ---------------------------------------------------------------------------
__global__ __launch_bounds__(256) void k_bias(
    const float* __restrict__ mask, const float* __restrict__ pb,
    bf16* __restrict__ T4)
{
  const int b = blockIdx.x, h = b >> 4, qt = b & 15;
  const int v = threadIdx.x;
  bf16 row[16];
  #pragma unroll
  for (int q16 = 0; q16 < 16; ++q16) {
    const int q = qt*16 + q16;
    row[q16] = (bf16)(mask[(size_t)q*256 + v] + pb[((size_t)q*256 + v)*4 + h]);
  }
  bf16* dst = T4 + ((size_t)b*256 + v)*16;
  *(bf16x8*)(dst)     = *(bf16x8*)(row);
  *(bf16x8*)(dst + 8) = *(bf16x8*)(row + 8);
}

// ---------------------------------------------------------------------------
// k_attn: block=(s,h), 4 waves x 64 q-rows. vT built in LDS from head-major v;
// bias slice staged coalesced via LDS; MFMA QK^T -> softmax -> MFMA PV.
// ---------------------------------------------------------------------------
__global__ __launch_bounds__(256) void k_attn(
    const bf16* __restrict__ qbh, const bf16* __restrict__ kbh,
    const bf16* __restrict__ vbh, const bf16* __restrict__ T4,
    bf16* __restrict__ aob)
{
  __shared__ bf16 qs[256 * 40];       // 20.0 KB
  __shared__ bf16 ps[4][16 * 264];    // 33.0 KB (also hosts vT during hoist)
  const int tid = threadIdx.x;
  const int s = blockIdx.x >> 2, h = blockIdx.x & 3;
  const int rb = s * 256;
  const bf16* qh = qbh + (size_t)h * P * 32;
  const bf16* kh = kbh + (size_t)h * P * 32;
  const bf16* vh = vbh + (size_t)h * P * 32;
  bf16* vT = &ps[0][0];               // [32][264], spans ps[0..1]

  // stage q (row-major, stride 40) and vT (transposed) from coalesced loads
  #pragma unroll
  for (int i = 0; i < 4; ++i) {
    const int flat = i*2048 + tid*8;
    const int pos = flat >> 5, cc = flat & 31;
    bf16x8 qv = *(const bf16x8*)(qh + ((size_t)rb + pos)*32 + cc);
    *(bf16x8*)(qs + pos*40 + cc) = qv;
    bf16x8 vv = *(const bf16x8*)(vh + ((size_t)rb + pos)*32 + cc);
    #pragma unroll
    for (int j = 0; j < 8; ++j) vT[(cc + j)*264 + pos] = vv[j];
  }
  __syncthreads();

  const int w = tid >> 6, lane = tid & 63, g = lane >> 4, l15 = lane & 15;

  // hoist PV A-fragments from vT
  bf16x8 av[2][8];
  #pragma unroll
  for (int mt = 0; mt < 2; ++mt)
    #pragma unroll
    for (int kt = 0; kt < 8; ++kt)
      av[mt][kt] = *(const bf16x8*)(vT + (16*mt + l15)*264 + 32*kt + 8*g);
  __syncthreads();   // vT region now reusable as ps

  bf16* psw = ps[w];
  const bf16* T4h = T4 + (size_t)h * 16 * 4096;
  bf16* aoh = aob + (size_t)h * P * 32;
  const f32x4 z = {0.f, 0.f, 0.f, 0.f};

  for (int qt = 0; qt < 4; ++qt) {
    const int q0 = w*64 + qt*16;

    // stage bias slice T4[h][q0>>4][v][q16] (8 KB) coalesced -> psw [v][16]
    const bf16* Tsl = T4h + (size_t)(q0 >> 4) * 4096;
    #pragma unroll
    for (int i = 0; i < 8; ++i) {
      const int flat = i*512 + lane*8;
      *(bf16x8*)(psw + flat) = *(const bf16x8*)(Tsl + flat);
    }

    // QK^T: scores for 16 q rows x all 256 v
    bf16x8 ak = *(const bf16x8*)(kh + ((size_t)rb + q0 + l15)*32 + 8*g);
    f32x4 sc[16];
    #pragma unroll
    for (int t = 0; t < 16; ++t) {
      bf16x8 bq = *(const bf16x8*)(qs + (16*t + l15)*40 + 8*g);
      sc[t] = MFMA(ak, bq, z);
    }

    // bias + exp + row sums  (q = q0+4g+r, v = 16t+l15)
    float rs0 = 0.f, rs1 = 0.f, rs2 = 0.f, rs3 = 0.f;
    #pragma unroll
    for (int t = 0; t < 16; ++t) {
      bf16x4 bb = *(const bf16x4*)(psw + (16*t + l15)*16 + 4*g);
      float e0 = __expf(sc[t][0] + (float)bb[0]); sc[t][0] = e0; rs0 += e0;
      float e1 = __expf(sc[t][1] + (float)bb[1]); sc[t][1] = e1; rs1 += e1;
      float e2 = __expf(sc[t][2] + (float)bb[2]); sc[t][2] = e2; rs2 += e2;
      float e3 = __expf(sc[t][3] + (float)bb[3]); sc[t][3] = e3; rs3 += e3;
    }
    #pragma unroll
    for (int m = 1; m < 16; m <<= 1) {
      rs0 += __shfl_xor(rs0, m, 16);
      rs1 += __shfl_xor(rs1, m, 16);
      rs2 += __shfl_xor(rs2, m, 16);
      rs3 += __shfl_xor(rs3, m, 16);
    }
    const float i0 = 1.f/rs0, i1 = 1.f/rs1, i2 = 1.f/rs2, i3 = 1.f/rs3;

    // normalized P (bf16) -> psw [q16][264]  (overwrites bias slice; same-wave
    // in-order LDS guarantees all bias reads completed)
    #pragma unroll
    for (int t = 0; t < 16; ++t) {
      const int vcol = 16*t + l15;
      psw[(4*g + 0)*264 + vcol] = (bf16)(sc[t][0] * i0);
      psw[(4*g + 1)*264 + vcol] = (bf16)(sc[t][1] * i1);
      psw[(4*g + 2)*264 + vcol] = (bf16)(sc[t][2] * i2);
      psw[(4*g + 3)*264 + vcol] = (bf16)(sc[t][3] * i3);
    }

    // PV: out^T[c][q16]
    f32x4 o0 = z, o1 = z;
    #pragma unroll
    for (int kt = 0; kt < 8; ++kt) {
      bf16x8 bp = *(const bf16x8*)(psw + l15*264 + 32*kt + 8*g);
      o0 = MFMA(av[0][kt], bp, o0);
      o1 = MFMA(av[1][kt], bp, o1);
    }
    bf16x4 p0, p1;
    p0[0] = (bf16)o0[0]; p0[1] = (bf16)o0[1]; p0[2] = (bf16)o0[2]; p0[3] = (bf16)o0[3];
    p1[0] = (bf16)o1[0]; p1[1] = (bf16)o1[1]; p1[2] = (bf16)o1[2]; p1[3] = (bf16)o1[3];
    bf16* dst = aoh + ((size_t)rb + q0 + l15)*32;
    *(bf16x4*)(dst + 4*g)      = p0;
    *(bf16x4*)(dst + 16 + 4*g) = p1;
  }
}

// ---------------------------------------------------------------------------
// k_gate_out: out = (ao * gate) @ Wo + bo via MFMA; WoF fragment-ordered.
// ---------------------------------------------------------------------------
__global__ __launch_bounds__(256) void k_gate_out(
    const bf16* __restrict__ aob, const bf16* __restrict__ gfb,
    const bf16* __restrict__ WoF, const float* __restrict__ bo,
    float* __restrict__ out)
{
  __shared__ bf16 gs[64 * 136];
  const int tid = threadIdx.x;
  const int base = blockIdx.x * 64;

  #pragma unroll
  for (int i = 0; i < 4; ++i) {
    const int flat = i*2048 + tid*8;
    const int pos = flat >> 7, c = flat & 127, h = c >> 5;
    bf16x8 a = *(const bf16x8*)(aob + ((size_t)h*P + base + pos)*32 + (c & 31));
    bf16x8 f = *(const bf16x8*)(gfb + ((size_t)(base + pos))*128 + c);
    bf16x8 o;
    #pragma unroll
    for (int j = 0; j < 8; ++j) o[j] = (bf16)((float)a[j] * (float)f[j]);
    *(bf16x8*)(gs + pos*136 + c) = o;
  }
  __syncthreads();

  const int w = tid >> 6, lane = tid & 63, g = lane >> 4, l15 = lane & 15;
  const f32x4 z = {0.f, 0.f, 0.f, 0.f};

  for (int nt = 0; nt < 4; ++nt) {
    bf16x8 bfr[4];
    #pragma unroll
    for (int kt = 0; kt < 4; ++kt)
      bfr[kt] = *(const bf16x8*)(gs + (16*nt + l15)*136 + 32*kt + 8*g);
    f32x4 a0 = z, a1 = z;
    #pragma unroll
    for (int kt = 0; kt < 4; ++kt) {
      bf16x8 af0 = *(const bf16x8*)(WoF + ((size_t)((2*w+0)*4 + kt)*64 + lane)*8);
      bf16x8 af1 = *(const bf16x8*)(WoF + ((size_t)((2*w+1)*4 + kt)*64 + lane)*8);
      a0 = MFMA(af0, bfr[kt], a0);
      a1 = MFMA(af1, bfr[kt], a1);
    }
    const int pos = base + 16*nt + l15;
    {
      const int col = 16*(2*w + 0) + 4*g;
      float4 bb = *(const float4*)(bo + col);
      *(float4*)(out + (size_t)pos*128 + col) =
          make_float4(a0[0] + bb.x, a0[1] + bb.y, a0[2] + bb.z, a0[3] + bb.w);
    }
    {
      const int col = 16*(2*w + 1) + 4*g;
      float4 bb = *(const float4*)(bo + col);
      *(float4*)(out + (size_t)pos*128 + col) =
          make_float4(a1[0] + bb.x, a1[1] + bb.y, a1[2] + bb.z, a1[3] + bb.w);
    }
  }
}

// ---------------------------------------------------------------------------
extern "C" void kernel_launch(void* const* d_in, const int* in_sizes, int n_in,
                              void* d_out, int out_size, void* d_ws, size_t ws_size,
                              hipStream_t stream) {
  const float* pr    = (const float*)d_in[0];
  const float* mask  = (const float*)d_in[1];
  const float* gamma = (const float*)d_in[2];
  const float* beta  = (const float*)d_in[3];
  const float* Wq    = (const float*)d_in[4];
  const float* Wk    = (const float*)d_in[5];
  const float* Wv    = (const float*)d_in[6];
  const float* Wb    = (const float*)d_in[7];
  const float* Wfu   = (const float*)d_in[8];
  const float* bfu   = (const float*)d_in[9];
  const float* Wo    = (const float*)d_in[10];
  const float* bo    = (const float*)d_in[11];
  float* out = (float*)d_out;

  bf16* qbh = (bf16*)d_ws;                        // H*P*32
  bf16* kbh = qbh + (size_t)H * P * 32;
  bf16* vbh = kbh + (size_t)H * P * 32;
  bf16* gfb = vbh + (size_t)H * P * 32;           // P*128
  bf16* aob = gfb + (size_t)P * 128;              // H*P*32
  bf16* T4  = aob + (size_t)H * P * 32;           // H*16*256*16 = H*P
  bf16* WF  = T4  + (size_t)H * P;                // 4*16384
  bf16* WoF = WF  + 4 * 16384;                    // 16384
  bf16* WbF = WoF + 16384;                        // 2048
  float* pb = (float*)(WbF + 2048);               // P*4 fp32

  k_prep<<<6, 256, 0, stream>>>(Wq, Wk, Wv, Wfu, Wo, Wb, WF, WoF, WbF);
  k_ln_proj<<<1024, 256, 0, stream>>>(pr, gamma, beta, bfu, WF, WbF,
                                      qbh, kbh, vbh, gfb, pb);
  k_bias<<<64, 256, 0, stream>>>(mask, pb, T4);
  k_attn<<<1024, 256, 0, stream>>>(qbh, kbh, vbh, T4, aob);
  k_gate_out<<<1024, 256, 0, stream>>>(aob, gfb, WoF, bo, out);
}